// Round 9
// baseline (222.626 us; speedup 1.0000x reference)
//
#include <hip/hip_runtime.h>
#include <cmath>
#include <cstdint>

#define BATCH  256
#define TT     1024
#define FIN    16
#define LSZ    256
#define NBULK  64
#define NCOH   32
#define TC     16
#define NCHUNK (TT / TC)          // 64
#define HBS    260                // s_hb row stride (floats)
#define HCS    68                 // s_hc row stride (floats)
#define YSS    336                // s_y row stride (bf16)

typedef __attribute__((ext_vector_type(8))) short short8;
typedef __attribute__((ext_vector_type(4))) float floatx4;

__device__ __forceinline__ unsigned short f2bf_rne(float f) {
    union { float f; unsigned int i; } v; v.f = f;
    unsigned int b = v.i;
    return (unsigned short)((b + 0x7FFFu + ((b >> 16) & 1u)) >> 16);
}
__device__ __forceinline__ unsigned int bfbits(float f) {  // round-half-up
    union { float f; unsigned int i; } v; v.f = f;
    return v.i + 0x8000u;
}

// Material constants (plane stress)
#define MC00   219.78021978021977f
#define MC01   65.93406593406593f
#define MC22   76.92307692307692f
#define MSY0   2.0f
#define AK     0.958466453674121406f  // 3G/(3G+H)
#define BK     0.041533546325878594f  // H/(3G+H)

__global__ __launch_bounds__(512, 1)
void fused_mat_kernel(const float* __restrict__ x,
                      const float* __restrict__ w1,
                      const float* __restrict__ w2,
                      float* __restrict__ out)
{
    // two independent pipelines (one per batch), each double-buffered
    __shared__ __attribute__((aligned(16))) float          s_hb[2][2][TC][HBS];  // 66560 B
    __shared__ __attribute__((aligned(16))) float          s_hc[2][2][TC][HCS];  // 17408 B
    __shared__ __attribute__((aligned(16))) unsigned short s_y [2][2][TC][YSS];  // 43008 B

    const int tid  = threadIdx.x;
    const int lane = tid & 63;
    const int wv8  = tid >> 6;       // 0..7
    const int p    = wv8 >> 2;       // pipeline 0/1
    const int role = wv8 & 3;        // 0: bulk, 1: cohesive, 2: h-GEMM, 3: out-GEMM
    const int m    = lane & 15;
    const int q    = lane >> 4;

    const int b = blockIdx.x * 2 + p;
    const size_t xrow = (size_t)b * TT;

    short8 w1f[16];   // role 2
    short8 vf[10];    // role 3 (permuted-k layout)
    uint4  rxa, rxb;  // role 2: raw x bits for next chunk

    if (role == 2) {
        #pragma unroll
        for (int n = 0; n < 16; ++n) {
            #pragma unroll
            for (int j = 0; j < 8; ++j) {
                unsigned short v = 0;
                if (q < 2) v = f2bf_rne(w1[(n * 16 + m) * FIN + q * 8 + j]);
                w1f[n][j] = (short)v;
            }
        }
        // prologue: produce chunk 0 into buffer 0
        short8 a0;
        #pragma unroll
        for (int j = 0; j < 8; ++j) {
            unsigned short v = 0;
            if (q < 2) v = f2bf_rne(x[(xrow + m) * FIN + q * 8 + j]);
            a0[j] = (short)v;
        }
        #pragma unroll
        for (int n = 0; n < 16; ++n) {
            floatx4 acc = {0.f, 0.f, 0.f, 0.f};
            acc = __builtin_amdgcn_mfma_f32_16x16x32_bf16(a0, w1f[n], acc, 0, 0, 0);
            const int col = n * 16 + m;
            if (n < 12) {
                const int cc = col / 3, cm = col - cc * 3;
                #pragma unroll
                for (int r = 0; r < 4; ++r)
                    s_hb[p][0][q * 4 + r][cc * 4 + cm] = acc[r];
            } else {
                #pragma unroll
                for (int r = 0; r < 4; ++r)
                    s_hc[p][0][q * 4 + r][col - 192] = acc[r];
            }
        }
        // prefetch raw x for chunk 1
        if (q < 2) {
            const float* xp = x + (xrow + TC + m) * FIN + q * 8;
            rxa = *(const uint4*)xp;
            rxb = *(const uint4*)(xp + 4);
        }
    } else if (role == 3) {
        #pragma unroll
        for (int ks = 0; ks < 10; ++ks) {
            #pragma unroll
            for (int j = 0; j < 8; ++j) {
                const int pp = ks * 32 + q * 8 + j;
                unsigned short v = 0;
                if (pp < 256) {
                    const int comp = pp & 3;
                    if (comp < 3) {
                        const int l = 3 * (pp >> 2) + comp;
                        float xv = w2[m * LSZ + l];
                        float sp = fmaxf(xv, 0.0f) + log1pf(expf(-fabsf(xv)));
                        v = f2bf_rne(sp);
                    }
                } else {
                    const int l = pp - 64;  // 192 + (pp-256)
                    float xv = w2[m * LSZ + l];
                    float sp = fmaxf(xv, 0.0f) + log1pf(expf(-fabsf(xv)));
                    v = f2bf_rne(sp);
                }
                vf[ks][j] = (short)v;
            }
        }
    }

    // material state
    float sg0 = 0.f, sg1 = 0.f, sg2 = 0.f, syv = MSY0;
    float ep0 = 0.f, ep1 = 0.f, ep2 = 0.f;   // role 0
    float hist = 0.f;                         // role 1
    floatx4 sacc = {0.f, 0.f, 0.f, 0.f};     // role 3: deferred-store accumulator

    __syncthreads();   // chunk 0 visible

    for (int i = 0; i <= NCHUNK; ++i) {
        if (role == 0) {
            if (i < NCHUNK) {
                const float* hb = &s_hb[p][i & 1][0][0];
                unsigned short* yb = &s_y[p][i & 1][0][0];
                const int off = lane * 4;
                floatx4 ev[TC];
                #pragma unroll
                for (int t = 0; t < TC; ++t)
                    ev[t] = *(const floatx4*)(hb + t * HBS + off);
                #pragma unroll
                for (int t = 0; t < TC; ++t) {
                    const float e0 = ev[t].x, e1 = ev[t].y, e2 = ev[t].z;
                    const float d0 = e0 - ep0, d1 = e1 - ep1, d2 = e2 - ep2;
                    ep0 = e0; ep1 = e1; ep2 = e2;
                    const float dl0 = fmaf(MC01, d1, MC00 * d0);
                    const float dl1 = fmaf(MC00, d1, MC01 * d0);
                    const float dl2 = MC22 * d2;
                    const float pre = AK * syv;
                    const float t0 = sg0 + dl0, t1 = sg1 + dl1, t2 = sg2 + dl2;
                    const float a1 = t0 * (t0 - t1);
                    const float b1 = fmaf(t1, t1, 3.0f * (t2 * t2));
                    const float qq = fmaxf(a1 + b1, 1e-12f);
                    const float rs  = __builtin_amdgcn_rsqf(qq);
                    const float seq = qq * rs;
                    const float rr  = fminf(fmaf(pre, rs, BK), 1.0f);
                    sg0 = rr * t0; sg1 = rr * t1; sg2 = rr * t2;
                    syv = fmaf(BK, fmaxf(seq - syv, 0.0f), syv);
                    uint2 pk;
                    pk.x = (bfbits(sg0) >> 16) | (bfbits(sg1) & 0xFFFF0000u);
                    pk.y = (bfbits(sg2) >> 16);
                    *(uint2*)(yb + t * YSS + off) = pk;
                }
            }
        } else if (role == 1) {
            if (i < NCHUNK && lane < NCOH) {
                const float* hc = &s_hc[p][i & 1][0][0];
                unsigned short* yb = &s_y[p][i & 1][0][0];
                const int off = 2 * lane;
                float2 jv[TC];
                #pragma unroll
                for (int t = 0; t < TC; ++t)
                    jv[t] = *(const float2*)(hc + t * HCS + off);
                #pragma unroll
                for (int t = 0; t < TC; ++t) {
                    const float dn = jv[t].x, ds = jv[t].y;
                    const float dnp = fmaxf(dn, 0.0f);
                    const float lam = __builtin_amdgcn_sqrtf(fmaxf(fmaf(dnp, dnp, ds * ds), 1e-12f));
                    hist = fmaxf(hist, lam);
                    float dmg = (hist - 0.1f) * __builtin_amdgcn_rcpf(hist * 0.9f);
                    dmg = fminf(fmaxf(dmg, 0.0f), 1.0f);
                    const float om = 1.0f - dmg;
                    const float tn = 50.0f * dn * (dn > 0.0f ? om : 1.0f);
                    const float ts = om * 50.0f * ds;
                    unsigned int pk = (bfbits(tn) >> 16) | (bfbits(ts) & 0xFFFF0000u);
                    *(unsigned int*)(yb + t * YSS + 256 + off) = pk;
                }
            }
        } else if (role == 2) {
            if (i + 1 < NCHUNK) {
                // convert prefetched raw x -> A-fragment for chunk i+1
                short8 af;
                {
                    const unsigned int w[8] = {rxa.x, rxa.y, rxa.z, rxa.w,
                                               rxb.x, rxb.y, rxb.z, rxb.w};
                    #pragma unroll
                    for (int j = 0; j < 8; ++j) {
                        unsigned short v = 0;
                        if (q < 2) {
                            union { unsigned int i; float f; } u; u.i = w[j];
                            v = f2bf_rne(u.f);
                        }
                        af[j] = (short)v;
                    }
                }
                // issue raw loads for chunk i+2 (consumed next interval)
                if (i + 2 < NCHUNK && q < 2) {
                    const float* xp = x + (xrow + (i + 2) * TC + m) * FIN + q * 8;
                    rxa = *(const uint4*)xp;
                    rxb = *(const uint4*)(xp + 4);
                }
                float* hbw = &s_hb[p][(i + 1) & 1][0][0];
                float* hcw = &s_hc[p][(i + 1) & 1][0][0];
                #pragma unroll
                for (int n = 0; n < 16; ++n) {
                    floatx4 acc = {0.f, 0.f, 0.f, 0.f};
                    acc = __builtin_amdgcn_mfma_f32_16x16x32_bf16(af, w1f[n], acc, 0, 0, 0);
                    const int col = n * 16 + m;
                    if (n < 12) {
                        const int cc = col / 3, cm = col - cc * 3;
                        #pragma unroll
                        for (int r = 0; r < 4; ++r)
                            hbw[(q * 4 + r) * HBS + cc * 4 + cm] = acc[r];
                    } else {
                        #pragma unroll
                        for (int r = 0; r < 4; ++r)
                            hcw[(q * 4 + r) * HCS + col - 192] = acc[r];
                    }
                }
            }
        } else {
            // deferred store of chunk i-2 (drained long before next barrier)
            if (i >= 2) {
                const int t0 = (i - 2) * TC;
                #pragma unroll
                for (int r = 0; r < 4; ++r)
                    out[(xrow + t0 + q * 4 + r) * FIN + m] = sacc[r];
            }
            if (i >= 1 && i <= NCHUNK) {
                const unsigned short* yb = &s_y[p][(i - 1) & 1][0][0];
                floatx4 a0 = {0.f, 0.f, 0.f, 0.f};
                floatx4 a1 = {0.f, 0.f, 0.f, 0.f};
                #pragma unroll
                for (int ks = 0; ks < 5; ++ks) {
                    const short8* yp = (const short8*)(yb + m * YSS + ks * 32 + q * 8);
                    a0 = __builtin_amdgcn_mfma_f32_16x16x32_bf16(*yp, vf[ks], a0, 0, 0, 0);
                }
                #pragma unroll
                for (int ks = 5; ks < 10; ++ks) {
                    const short8* yp = (const short8*)(yb + m * YSS + ks * 32 + q * 8);
                    a1 = __builtin_amdgcn_mfma_f32_16x16x32_bf16(*yp, vf[ks], a1, 0, 0, 0);
                }
                #pragma unroll
                for (int r = 0; r < 4; ++r) sacc[r] = a0[r] + a1[r];
            }
        }
        __syncthreads();
    }

    // epilogue: store the final chunk's output (computed at i = NCHUNK)
    if (role == 3) {
        const int t0 = (NCHUNK - 1) * TC;
        #pragma unroll
        for (int r = 0; r < 4; ++r)
            out[(xrow + t0 + q * 4 + r) * FIN + m] = sacc[r];
    }
}

extern "C" void kernel_launch(void* const* d_in, const int* in_sizes, int n_in,
                              void* d_out, int out_size, void* d_ws, size_t ws_size,
                              hipStream_t stream) {
    const float* x  = (const float*)d_in[0];   // [256,1024,16] f32
    const float* w1 = (const float*)d_in[1];   // [256,16] f32
    const float* w2 = (const float*)d_in[2];   // [16,256] f32
    float* out = (float*)d_out;                // [256,1024,16] f32
    fused_mat_kernel<<<BATCH / 2, 512, 0, stream>>>(x, w1, w2, out);
}

// Round 10
// 160.587 us; speedup vs baseline: 1.3863x; 1.3863x over previous
//
#include <hip/hip_runtime.h>
#include <cmath>
#include <cstdint>

#define BATCH  256
#define TT     1024
#define FIN    16
#define LSZ    256
#define NBULK  64
#define NCOH   32
#define TC     32
#define NCHUNK (TT / TC)          // 32
#define HBS    260                // s_hb row stride (floats)
#define HCS    68                 // s_hc row stride (floats)
#define YSS    336                // s_y row stride (bf16)

typedef __attribute__((ext_vector_type(8))) short short8;
typedef __attribute__((ext_vector_type(4))) float floatx4;

__device__ __forceinline__ unsigned short f2bf_rne(float f) {
    union { float f; unsigned int i; } v; v.f = f;
    unsigned int b = v.i;
    return (unsigned short)((b + 0x7FFFu + ((b >> 16) & 1u)) >> 16);
}
__device__ __forceinline__ unsigned int bfbits(float f) {  // round-half-up
    union { float f; unsigned int i; } v; v.f = f;
    return v.i + 0x8000u;
}
__device__ __forceinline__ float u2f(unsigned int u) {
    union { unsigned int i; float f; } v; v.i = u; return v.f;
}

// raw barrier: LDS-ordered only — global loads/stores stay in flight
#define BARRIER() asm volatile("s_waitcnt lgkmcnt(0)\n\ts_barrier" ::: "memory")

// Material constants (plane stress)
#define MC00   219.78021978021977f
#define MC01   65.93406593406593f
#define MC22   76.92307692307692f
#define MSY0   2.0f
#define AK     0.958466453674121406f  // 3G/(3G+H)
#define BK     0.041533546325878594f  // H/(3G+H)

__global__ __launch_bounds__(256, 1)
void fused_mat_kernel(const float* __restrict__ x,
                      const float* __restrict__ w1,
                      const float* __restrict__ w2,
                      float* __restrict__ out)
{
    __shared__ __attribute__((aligned(16))) float          s_hb[2][TC][HBS];  // dl triplets
    __shared__ __attribute__((aligned(16))) float          s_hc[2][TC][HCS];  // abs jumps
    __shared__ __attribute__((aligned(16))) unsigned short s_y [2][TC][YSS];  // bf16 y

    const int tid  = threadIdx.x;
    const int b    = blockIdx.x;
    const int lane = tid & 63;
    const int wv   = tid >> 6;    // 0: bulk, 1: cohesive, 2: h-GEMM, 3: out-GEMM
    const int m    = lane & 15;
    const int q    = lane >> 4;

    const size_t xrow = (size_t)b * TT;

    short8 w1fd[12];  // wave 2: C-folded W1 (bulk cols), fed with delta-x
    short8 w1f4[4];   // wave 2: plain W1 (cohesive cols), fed with abs-x
    short8 vf[10];    // wave 3 (permuted-k layout)
    uint4  rxc[2][2], rxp[2][2];  // wave 2: raw x bits, cur/prev row, per M-tile

    if (wv == 2) {
        // ---- C-folded W1 fragments for bulk columns (n<12) ----
        #pragma unroll
        for (int n = 0; n < 12; ++n) {
            #pragma unroll
            for (int j = 0; j < 8; ++j) {
                float v = 0.f;
                if (q < 2) {
                    const int l = n * 16 + m, c = l / 3, cm = l - 3 * c, f = q * 8 + j;
                    const float wa = w1[(3 * c + 0) * FIN + f];
                    const float wb = w1[(3 * c + 1) * FIN + f];
                    const float wc = w1[(3 * c + 2) * FIN + f];
                    v = (cm == 0) ? fmaf(MC01, wb, MC00 * wa)
                      : (cm == 1) ? fmaf(MC00, wb, MC01 * wa)
                                  : MC22 * wc;
                }
                w1fd[n][j] = (short)f2bf_rne(v);
            }
        }
        // ---- plain W1 fragments for cohesive columns (n>=12) ----
        #pragma unroll
        for (int n = 12; n < 16; ++n) {
            #pragma unroll
            for (int j = 0; j < 8; ++j) {
                unsigned short v = 0;
                if (q < 2) v = f2bf_rne(w1[(n * 16 + m) * FIN + q * 8 + j]);
                w1f4[n - 12][j] = (short)v;
            }
        }
        // ---- prologue: produce chunk 0 ----
        #pragma unroll
        for (int mt = 0; mt < 2; ++mt) {
            short8 ax, adx;
            #pragma unroll
            for (int j = 0; j < 8; ++j) {
                float xc = 0.f, xp = 0.f;
                if (q < 2) {
                    const int rowB = mt * 16 + m;
                    xc = x[(xrow + rowB) * FIN + q * 8 + j];
                    if (rowB > 0) xp = x[(xrow + rowB - 1) * FIN + q * 8 + j];
                }
                ax[j]  = (short)f2bf_rne(xc);
                adx[j] = (short)f2bf_rne(xc - xp);
            }
            #pragma unroll
            for (int n = 0; n < 16; ++n) {
                floatx4 acc = {0.f, 0.f, 0.f, 0.f};
                acc = (n < 12)
                    ? __builtin_amdgcn_mfma_f32_16x16x32_bf16(adx, w1fd[n], acc, 0, 0, 0)
                    : __builtin_amdgcn_mfma_f32_16x16x32_bf16(ax, w1f4[n - 12], acc, 0, 0, 0);
                const int col = n * 16 + m;
                if (n < 12) {
                    const int cc = col / 3, cm = col - cc * 3;
                    #pragma unroll
                    for (int r = 0; r < 4; ++r)
                        s_hb[0][mt * 16 + q * 4 + r][cc * 4 + cm] = acc[r];
                } else {
                    #pragma unroll
                    for (int r = 0; r < 4; ++r)
                        s_hc[0][mt * 16 + q * 4 + r][col - 192] = acc[r];
                }
            }
        }
        // ---- prefetch raw x rows for chunk 1 ----
        if (q < 2) {
            #pragma unroll
            for (int mt = 0; mt < 2; ++mt) {
                const int rowB = TC + mt * 16 + m;
                const float* xc = x + (xrow + rowB) * FIN + q * 8;
                const float* xp = x + (xrow + rowB - 1) * FIN + q * 8;
                rxc[mt][0] = *(const uint4*)xc;  rxc[mt][1] = *(const uint4*)(xc + 4);
                rxp[mt][0] = *(const uint4*)xp;  rxp[mt][1] = *(const uint4*)(xp + 4);
            }
        }
    } else if (wv == 3) {
        #pragma unroll
        for (int ks = 0; ks < 10; ++ks) {
            #pragma unroll
            for (int j = 0; j < 8; ++j) {
                const int p = ks * 32 + q * 8 + j;
                unsigned short v = 0;
                if (p < 256) {
                    const int comp = p & 3;
                    if (comp < 3) {
                        const int l = 3 * (p >> 2) + comp;
                        float xv = w2[m * LSZ + l];
                        float sp = fmaxf(xv, 0.0f) + log1pf(expf(-fabsf(xv)));
                        v = f2bf_rne(sp);
                    }
                } else {
                    const int l = p - 64;  // 192 + (p-256)
                    float xv = w2[m * LSZ + l];
                    float sp = fmaxf(xv, 0.0f) + log1pf(expf(-fabsf(xv)));
                    v = f2bf_rne(sp);
                }
                vf[ks][j] = (short)v;
            }
        }
    }

    // material state
    float sg0 = 0.f, sg1 = 0.f, sg2 = 0.f, syv = MSY0;  // wave 0 (sigma-space J2)
    float hist = 0.f;                                    // wave 1

    __syncthreads();   // chunk 0 visible (full barrier once)

    for (int i = 0; i <= NCHUNK; ++i) {
        if (wv == 0) {
            if (i < NCHUNK) {
                const float* hb = &s_hb[i & 1][0][0];
                unsigned short* yb = &s_y[i & 1][0][0];
                const int off = lane * 4;
                #pragma unroll
                for (int t = 0; t < TC; ++t) {
                    const floatx4 dv = *(const floatx4*)(hb + t * HBS + off);  // dl0,dl1,dl2,pad
                    const float pre = AK * syv;
                    const float t0 = sg0 + dv.x, t1 = sg1 + dv.y, t2 = sg2 + dv.z;
                    const float a1 = t0 * (t0 - t1);
                    const float b1 = fmaf(t1, t1, 3.0f * (t2 * t2));
                    const float qq = fmaxf(a1 + b1, 1e-12f);
                    const float rs  = __builtin_amdgcn_rsqf(qq);
                    const float seq = qq * rs;
                    const float rr  = fminf(fmaf(pre, rs, BK), 1.0f);
                    sg0 = rr * t0; sg1 = rr * t1; sg2 = rr * t2;
                    syv = fmaf(BK, fmaxf(seq - syv, 0.0f), syv);
                    uint2 pk;
                    pk.x = (bfbits(sg0) >> 16) | (bfbits(sg1) & 0xFFFF0000u);
                    pk.y = (bfbits(sg2) >> 16);
                    *(uint2*)(yb + t * YSS + off) = pk;
                }
            }
        } else if (wv == 1) {
            if (i < NCHUNK && lane < NCOH) {
                const float* hc = &s_hc[i & 1][0][0];
                unsigned short* yb = &s_y[i & 1][0][0];
                const int off = 2 * lane;
                #pragma unroll
                for (int t = 0; t < TC; ++t) {
                    const float2 jv = *(const float2*)(hc + t * HCS + off);
                    const float dn = jv.x, ds = jv.y;
                    const float dnp = fmaxf(dn, 0.0f);
                    const float lam = __builtin_amdgcn_sqrtf(fmaxf(fmaf(dnp, dnp, ds * ds), 1e-12f));
                    hist = fmaxf(hist, lam);
                    float dmg = (hist - 0.1f) * __builtin_amdgcn_rcpf(hist * 0.9f);
                    dmg = fminf(fmaxf(dmg, 0.0f), 1.0f);
                    const float om = 1.0f - dmg;
                    const float tn = 50.0f * dn * (dn > 0.0f ? om : 1.0f);
                    const float ts = om * 50.0f * ds;
                    unsigned int pk = (bfbits(tn) >> 16) | (bfbits(ts) & 0xFFFF0000u);
                    *(unsigned int*)(yb + t * YSS + 256 + off) = pk;
                }
            }
        } else if (wv == 2) {
            if (i + 1 < NCHUNK) {
                // convert prefetched raw x -> abs & delta A-fragments for chunk i+1
                short8 ax[2], adx[2];
                #pragma unroll
                for (int mt = 0; mt < 2; ++mt) {
                    const unsigned int wc[8] = {rxc[mt][0].x, rxc[mt][0].y, rxc[mt][0].z, rxc[mt][0].w,
                                                rxc[mt][1].x, rxc[mt][1].y, rxc[mt][1].z, rxc[mt][1].w};
                    const unsigned int wp[8] = {rxp[mt][0].x, rxp[mt][0].y, rxp[mt][0].z, rxp[mt][0].w,
                                                rxp[mt][1].x, rxp[mt][1].y, rxp[mt][1].z, rxp[mt][1].w};
                    #pragma unroll
                    for (int j = 0; j < 8; ++j) {
                        unsigned short va = 0, vd = 0;
                        if (q < 2) {
                            const float xc = u2f(wc[j]), xp = u2f(wp[j]);
                            va = f2bf_rne(xc);
                            vd = f2bf_rne(xc - xp);
                        }
                        ax[mt][j]  = (short)va;
                        adx[mt][j] = (short)vd;
                    }
                }
                // issue raw loads for chunk i+2 (stay in flight across the raw barrier)
                if (i + 2 < NCHUNK && q < 2) {
                    #pragma unroll
                    for (int mt = 0; mt < 2; ++mt) {
                        const int rowB = (i + 2) * TC + mt * 16 + m;
                        const float* xc = x + (xrow + rowB) * FIN + q * 8;
                        const float* xp = x + (xrow + rowB - 1) * FIN + q * 8;
                        rxc[mt][0] = *(const uint4*)xc;  rxc[mt][1] = *(const uint4*)(xc + 4);
                        rxp[mt][0] = *(const uint4*)xp;  rxp[mt][1] = *(const uint4*)(xp + 4);
                    }
                }
                float* hbw = &s_hb[(i + 1) & 1][0][0];
                float* hcw = &s_hc[(i + 1) & 1][0][0];
                #pragma unroll
                for (int mt = 0; mt < 2; ++mt) {
                    #pragma unroll
                    for (int n = 0; n < 16; ++n) {
                        floatx4 acc = {0.f, 0.f, 0.f, 0.f};
                        acc = (n < 12)
                            ? __builtin_amdgcn_mfma_f32_16x16x32_bf16(adx[mt], w1fd[n], acc, 0, 0, 0)
                            : __builtin_amdgcn_mfma_f32_16x16x32_bf16(ax[mt], w1f4[n - 12], acc, 0, 0, 0);
                        const int col = n * 16 + m;
                        if (n < 12) {
                            const int cc = col / 3, cm = col - cc * 3;
                            #pragma unroll
                            for (int r = 0; r < 4; ++r)
                                hbw[(mt * 16 + q * 4 + r) * HBS + cc * 4 + cm] = acc[r];
                        } else {
                            #pragma unroll
                            for (int r = 0; r < 4; ++r)
                                hcw[(mt * 16 + q * 4 + r) * HCS + col - 192] = acc[r];
                        }
                    }
                }
            }
        } else {
            if (i >= 1) {
                const int t0 = (i - 1) * TC;
                const unsigned short* yb = &s_y[(i - 1) & 1][0][0];
                #pragma unroll
                for (int mt = 0; mt < 2; ++mt) {
                    floatx4 a0 = {0.f, 0.f, 0.f, 0.f};
                    floatx4 a1 = {0.f, 0.f, 0.f, 0.f};
                    #pragma unroll
                    for (int ks = 0; ks < 5; ++ks) {
                        const short8* yp = (const short8*)(yb + (mt * 16 + m) * YSS + ks * 32 + q * 8);
                        a0 = __builtin_amdgcn_mfma_f32_16x16x32_bf16(*yp, vf[ks], a0, 0, 0, 0);
                    }
                    #pragma unroll
                    for (int ks = 5; ks < 10; ++ks) {
                        const short8* yp = (const short8*)(yb + (mt * 16 + m) * YSS + ks * 32 + q * 8);
                        a1 = __builtin_amdgcn_mfma_f32_16x16x32_bf16(*yp, vf[ks], a1, 0, 0, 0);
                    }
                    #pragma unroll
                    for (int r = 0; r < 4; ++r)
                        out[(xrow + t0 + mt * 16 + q * 4 + r) * FIN + m] = a0[r] + a1[r];
                }
            }
        }
        BARRIER();   // lgkmcnt(0) only — global ops stay in flight
    }
}

extern "C" void kernel_launch(void* const* d_in, const int* in_sizes, int n_in,
                              void* d_out, int out_size, void* d_ws, size_t ws_size,
                              hipStream_t stream) {
    const float* x  = (const float*)d_in[0];   // [256,1024,16] f32
    const float* w1 = (const float*)d_in[1];   // [256,16] f32
    const float* w2 = (const float*)d_in[2];   // [16,256] f32
    float* out = (float*)d_out;                // [256,1024,16] f32
    fused_mat_kernel<<<BATCH, 256, 0, stream>>>(x, w1, w2, out);
}